// Round 11
// baseline (212.976 us; speedup 1.0000x reference)
//
#include <hip/hip_runtime.h>
#include <cstdint>
#include <cstddef>

#define D_MODEL 1024
#define N_HEADS 16
#define HEAD_DIM 64
#define SEQ 2048
#define BATCH 2

typedef __attribute__((ext_vector_type(8))) short bf16x8;
typedef __attribute__((ext_vector_type(4))) float f32x4;

// Hardware bf16 convert (RNE): 1 VALU op per 2 elements.
__device__ __forceinline__ unsigned cvtpk_bf16(float lo, float hi) {
    unsigned r;
    asm("v_cvt_pk_bf16_f32 %0, %1, %2" : "=v"(r) : "v"(lo), "v"(hi));
    return r;
}
__device__ __forceinline__ unsigned short f2bf_hw(float f) {
    return (unsigned short)cvtpk_bf16(f, 0.f);
}

// async global->LDS, 16 B per lane; LDS dst must be wave-base + lane*16.
__device__ __forceinline__ void gload_lds16(const unsigned short* g, unsigned short* l) {
    __builtin_amdgcn_global_load_lds(
        (const __attribute__((address_space(1))) unsigned int*)g,
        (__attribute__((address_space(3))) unsigned int*)l, 16, 0, 0);
}

// s_waitcnt immediates (gfx9: vmcnt[3:0]|[15:14], expcnt[6:4], lgkmcnt[11:8])
#define WAITCNT_VM8 0x0F78   // vmcnt(8)
#define WAITCNT_VM4 0x0F74   // vmcnt(4)
#define WAITCNT_VM0 0x0F70   // vmcnt(0)

// ---------------------------------------------------------------------------
// Fused converts: x->bf16 | w_qkv->Wqt (permuted transpose, Q pre-scaled) |
// w_proj->Wpt.
// ---------------------------------------------------------------------------
__global__ __launch_bounds__(256) void fused_convert_kernel(
    const float* __restrict__ X, unsigned short* __restrict__ Xb,
    const float* __restrict__ Wq, unsigned short* __restrict__ Wqt,
    const float* __restrict__ Wp, unsigned short* __restrict__ Wpt)
{
    const int blk = blockIdx.x;
    const int tid = threadIdx.x;
    __shared__ float t[32][33];

    if (blk < 2048) {
        const int idx = blk * 256 + tid;
        const float4* src = (const float4*)X;
        float4 v0 = src[idx * 2], v1 = src[idx * 2 + 1];
        uint4 o;
        o.x = cvtpk_bf16(v0.x, v0.y);
        o.y = cvtpk_bf16(v0.z, v0.w);
        o.z = cvtpk_bf16(v1.x, v1.y);
        o.w = cvtpk_bf16(v1.z, v1.w);
        ((uint4*)Xb)[idx] = o;
    } else if (blk < 5120) {
        const int bb = blk - 2048;
        const int c0 = (bb % 96) * 32, r0 = (bb / 96) * 32;
        const int a = tid & 31, b = tid >> 5;
#pragma unroll
        for (int i = 0; i < 32; i += 8)
            t[b + i][a] = Wq[(size_t)(r0 + b + i) * (3 * D_MODEL) + c0 + a];
        __syncthreads();
#pragma unroll
        for (int i = 0; i < 32; i += 8) {
            const int c = c0 + b + i;
            const int which = c % 3;
            const int np = which * 1024 + c / 3;   // which*1024 + h*64 + d
            const float s = (which == 0) ? 0.125f : 1.0f;
            Wqt[(size_t)np * D_MODEL + r0 + a] = f2bf_hw(t[a][b + i] * s);
        }
    } else {
        const int bb = blk - 5120;
        const int c0 = (bb % 32) * 32, r0 = (bb / 32) * 32;
        const int a = tid & 31, b = tid >> 5;
#pragma unroll
        for (int i = 0; i < 32; i += 8)
            t[b + i][a] = Wp[(size_t)(r0 + b + i) * D_MODEL + c0 + a];
        __syncthreads();
#pragma unroll
        for (int i = 0; i < 32; i += 8)
            Wpt[(size_t)(c0 + b + i) * D_MODEL + r0 + a] = f2bf_hw(t[a][b + i]);
    }
}

// ---------------------------------------------------------------------------
// Pipelined GEMM core (R2/R4-proven, kept for gemm_proj): 128x128, BK=32,
// triple-buffer, depth-2 prefetch, counted vmcnt(4), setprio around MFMA.
// ---------------------------------------------------------------------------
#define GEMM_PIPE3_BODY(A_, B_, KBASE, NITER, BX_, BY_)                        \
    const int tid = threadIdx.x;                                               \
    const int w = tid >> 6, lane = tid & 63;                                   \
    const int l15 = lane & 15, quad = lane >> 4;                               \
    const int wr = w >> 1, wc = w & 1;                                         \
    const int row0 = (BY_) * 128, col0 = (BX_) * 128;                          \
    __shared__ unsigned short As[3][4096];                                     \
    __shared__ unsigned short Bs[3][4096];                                     \
    const f32x4 zero4 = {0.f, 0.f, 0.f, 0.f};                                  \
    f32x4 acc[4][4];                                                           \
    _Pragma("unroll") for (int i = 0; i < 4; i++)                              \
        _Pragma("unroll") for (int j = 0; j < 4; j++) acc[i][j] = zero4;       \
    auto stage_ = [&](int sb_, int kt_) {                                      \
        const int k0 = (KBASE) + kt_ * 32 + quad * 8;                          \
        _Pragma("unroll") for (int i = 0; i < 2; i++) {                        \
            const int f = w * 2 + i;                                           \
            gload_lds16((A_) + (size_t)(row0 + f * 16 + l15) * D_MODEL + k0,   \
                        &As[sb_][f * 512 + lane * 8]);                         \
            gload_lds16((B_) + (size_t)(col0 + f * 16 + l15) * D_MODEL + k0,   \
                        &Bs[sb_][f * 512 + lane * 8]);                         \
        }                                                                      \
    };                                                                         \
    stage_(0, 0);                                                              \
    stage_(1, 1);                                                              \
    int sb = 0;                                                                \
    for (int kt = 0; kt < (NITER); kt++) {                                     \
        if (kt < (NITER) - 1) {                                                \
            __builtin_amdgcn_s_waitcnt(WAITCNT_VM4);                           \
            __builtin_amdgcn_s_barrier();                                      \
            if (kt + 2 < (NITER)) stage_((sb + 2 > 2) ? sb - 1 : sb + 2, kt + 2); \
        } else {                                                               \
            __builtin_amdgcn_s_waitcnt(WAITCNT_VM0);                           \
            __builtin_amdgcn_s_barrier();                                      \
        }                                                                      \
        bf16x8 af[4], bfr[4];                                                  \
        _Pragma("unroll") for (int i = 0; i < 4; i++)                          \
            af[i] = *(const bf16x8*)&As[sb][(wr * 4 + i) * 512 + lane * 8];    \
        _Pragma("unroll") for (int j = 0; j < 4; j++)                          \
            bfr[j] = *(const bf16x8*)&Bs[sb][(wc * 4 + j) * 512 + lane * 8];   \
        __builtin_amdgcn_s_setprio(1);                                         \
        _Pragma("unroll") for (int i = 0; i < 4; i++)                          \
            _Pragma("unroll") for (int j = 0; j < 4; j++)                      \
                acc[i][j] = __builtin_amdgcn_mfma_f32_16x16x32_bf16(           \
                    af[i], bfr[j], acc[i][j], 0, 0, 0);                        \
        __builtin_amdgcn_s_setprio(0);                                         \
        sb = (sb == 2) ? 0 : sb + 1;                                           \
    }

// ---------------------------------------------------------------------------
// GEMM1 v2: 256x256 tile, BK=64, 8 waves (512 thr, 2M x 4N), K-HALF UNIT
// PIPELINE (T3+T4): 32 consumption units (K-halves of 32), each = A-half +
// B-half = 4 gloads/thread, staged 3 units ahead. Per-unit: counted
// vmcnt(8) (12 in flight -> drain oldest unit; vm4/vm0 only for the last 2
// units) -> barrier -> stage unit u+3 -> 12 ds_read_b128 -> 32 MFMA
// (setprio-wrapped). One barrier per unit = 2 per K-tile, 32 MFMA/wave
// between barriers (2x PIPE3).
// Race-freedom: unit u+3 overwrites unit u-1's slot; u-1's ds_reads are
// lgkm-retired before each wave's barrier-u arrival, and stages issue only
// post-barrier. LDS: A 2x32KB + B 2x32KB = 128KB -> 1 block/CU.
// Frag-order LDS (as PIPE3): conflict-free ds_read_b128, gload-compatible.
// Grid 12x16 = 192 blocks; XCD-bijective 3(bx) x 8(by) rectangles.
// ---------------------------------------------------------------------------
__global__ __launch_bounds__(512, 2) void gemm_qkv_mfma(
    const unsigned short* __restrict__ A, const unsigned short* __restrict__ B,
    unsigned short* __restrict__ Q, unsigned short* __restrict__ Kq,
    unsigned short* __restrict__ Vt)
{
    const int lin = blockIdx.x + 12 * blockIdx.y;   // 0..191, %8 = XCD
    const int xcd = lin & 7, t8 = lin >> 3;         // t8: 0..23
    const int bx = (xcd & 3) * 3 + t8 % 3;          // 0..11
    const int by = (xcd >> 2) * 8 + t8 / 3;         // 0..15

    const int tid = threadIdx.x;
    const int w = tid >> 6, lane = tid & 63;        // w: 0..7
    const int l15 = lane & 15, quad = lane >> 4;
    const int wr = w >> 2, wc = w & 3;              // 2M x 4N wave grid
    const int row0 = by * 256, col0 = bx * 256;

    __shared__ unsigned short As[2 * 16384];        // 2 bufs x 256x64 bf16
    __shared__ unsigned short Bs[2 * 16384];

    const f32x4 zero4 = {0.f, 0.f, 0.f, 0.f};
    f32x4 acc[8][4];
#pragma unroll
    for (int i = 0; i < 8; i++)
#pragma unroll
        for (int j = 0; j < 4; j++) acc[i][j] = zero4;

    // stage one unit: A k-half + B k-half of tile kt (4 gloads/thread).
    // sub-block fb = f*2 + kh (f = m/n frag, kh = k-half), 512 shorts each.
    auto stage_u = [&](int bf, int kt, int kh) {
        const int k0 = kt * 64 + kh * 32 + quad * 8;
#pragma unroll
        for (int i = 0; i < 2; i++) {
            const int f = w * 2 + i;
            gload_lds16(A + (size_t)(row0 + f * 16 + l15) * D_MODEL + k0,
                        &As[bf * 16384 + (f * 2 + kh) * 512 + lane * 8]);
        }
#pragma unroll
        for (int i = 0; i < 2; i++) {
            const int f = w * 2 + i;
            gload_lds16(B + (size_t)(col0 + f * 16 + l15) * D_MODEL + k0,
                        &Bs[bf * 16384 + (f * 2 + kh) * 512 + lane * 8]);
        }
    };

    auto compute_u = [&](int bf, int kh) {
        bf16x8 af[8], bfr[4];
#pragma unroll
        for (int i = 0; i < 8; i++)
            af[i] = *(const bf16x8*)&As[bf * 16384 + ((wr * 8 + i) * 2 + kh) * 512 + lane * 8];
#pragma unroll
        for (int j = 0; j < 4; j++)
            bfr[j] = *(const bf16x8*)&Bs[bf * 16384 + ((wc * 4 + j) * 2 + kh) * 512 + lane * 8];
        __builtin_amdgcn_s_setprio(1);
#pragma unroll
        for (int i = 0; i < 8; i++)
#pragma unroll
            for (int j = 0; j < 4; j++)
                acc[i][j] = __builtin_amdgcn_mfma_f32_16x16x32_bf16(
                    af[i], bfr[j], acc[i][j], 0, 0, 0);
        __builtin_amdgcn_s_setprio(0);
    };

    // prologue: units 0,1,2 (12 loads/thread in flight)
    stage_u(0, 0, 0);
    stage_u(0, 0, 1);
    stage_u(1, 1, 0);

    for (int t = 0; t < 16; t++) {
        const int bf = t & 1;
        // ---- unit u = 2t (kh=0) ----
        if (t < 15) __builtin_amdgcn_s_waitcnt(WAITCNT_VM8);
        else        __builtin_amdgcn_s_waitcnt(WAITCNT_VM4);
        __builtin_amdgcn_s_barrier();
        if (t + 1 < 16) stage_u((t + 1) & 1, t + 1, 1);   // unit 2t+3
        compute_u(bf, 0);
        // ---- unit u = 2t+1 (kh=1) ----
        if (t < 15) __builtin_amdgcn_s_waitcnt(WAITCNT_VM8);
        else        __builtin_amdgcn_s_waitcnt(WAITCNT_VM0);
        __builtin_amdgcn_s_barrier();
        if (t + 2 < 16) stage_u((t + 2) & 1, t + 2, 0);   // unit 2t+4
        compute_u(bf, 1);
    }

    // ---- epilogue ----
    const int which = col0 >> 10;                  // 0:Q 1:K 2:V (block-uniform)
    const int nbase = col0 + wc * 64;              // wave col window (mult 64)
    const int bb = row0 >> 11;                     // block-uniform (256 | 2048)
    if (which < 2) {
        unsigned short* const dst = (which == 0) ? Q : Kq;
#pragma unroll
        for (int i = 0; i < 8; i++) {
            const int rowb = row0 + wr * 128 + i * 16 + quad * 4;
            const int n = rowb & (SEQ - 1);
#pragma unroll
            for (int rp = 0; rp < 2; rp++) {
#pragma unroll
                for (int j = 0; j < 4; j++) {
                    const unsigned u = cvtpk_bf16(acc[i][j][2 * rp], acc[i][j][2 * rp + 1]);
                    const int idx = (nbase + j * 16 + l15) & 1023;  // h*64+d
                    const int h = idx >> 6, dd = idx & 63;
                    unsigned short* p =
                        dst + (((size_t)(bb * N_HEADS + h)) * SEQ + n + 2 * rp) * HEAD_DIM + dd;
                    p[0] = (unsigned short)u;
                    p[HEAD_DIM] = (unsigned short)(u >> 16);
                }
            }
        }
    } else {
        // V direct-transpose: 4 chunks of 64 cols through LDS [64][264]
        // (R7-proven pattern scaled to 256x256; 264-short stride = 528B,
        // 16B-multiple so uint4 readout stays aligned).
        unsigned short* vt = &As[0];               // 64*264*2 = 33.8KB < 64KB
        const int n0 = row0 & (SEQ - 1);
        const int vbase = col0 & 1023;             // h*64+d base (mult 256)
        __syncthreads();                           // K-loop LDS reads done
#pragma unroll
        for (int ch = 0; ch < 4; ch++) {
            if (wc == ch) {                        // 2 waves (wr=0,1) write
#pragma unroll
                for (int i = 0; i < 8; i++) {
                    const int nl = wr * 128 + i * 16 + quad * 4;
#pragma unroll
                    for (int rp = 0; rp < 2; rp++) {
#pragma unroll
                        for (int j = 0; j < 4; j++) {
                            const unsigned u =
                                cvtpk_bf16(acc[i][j][2 * rp], acc[i][j][2 * rp + 1]);
                            const int c_loc = j * 16 + l15;          // 0..63
                            *(unsigned*)&vt[c_loc * 264 + nl + 2 * rp] = u;
                        }
                    }
                }
            }
            __syncthreads();
            // all 512 threads: 64 cols x 32 uint4 (256 n each col)
#pragma unroll
            for (int pass = 0; pass < 4; pass++) {
                const int idx2 = pass * 512 + tid;           // 0..2047
                const int c_loc = idx2 >> 5, seg = idx2 & 31;
                const uint4 v = *(const uint4*)&vt[c_loc * 264 + seg * 8];
                const int vc = vbase + ch * 64 + c_loc;      // h*64+d
                *(uint4*)&Vt[((size_t)(bb * N_HEADS + (vc >> 6)) * HEAD_DIM
                              + (vc & 63)) * SEQ + n0 + seg * 8] = v;
            }
            if (ch < 3) __syncthreads();           // before next chunk writes
        }
    }
}

// GEMM2: SPLIT-K=2, PIPE3. Grid (8, 32, 2). K=512/block, NITER=16.
// T1 XCD swizzle per z-slice: 32/XCD as 4(bx) x 8(by) rectangle.
__global__ __launch_bounds__(256) void gemm_proj_splitk(
    const unsigned short* __restrict__ A, const unsigned short* __restrict__ B,
    float* __restrict__ P)
{
    const int lin = blockIdx.x + 8 * blockIdx.y;    // 0..255, %8 = XCD
    const int xcd = lin & 7, t = lin >> 3;          // t: 0..31
    const int bx = (xcd & 1) * 4 + t % 4;           // 0..7
    const int by = (xcd >> 1) * 8 + t / 4;          // 0..31
    const int kbase = blockIdx.z * 512;
    GEMM_PIPE3_BODY(A, B, kbase, 16, bx, by)
    float* const dst = P + (size_t)blockIdx.z * (4096ull * 1024ull);
#pragma unroll
    for (int i = 0; i < 4; i++) {
#pragma unroll
        for (int r = 0; r < 4; r++) {
            const int row = row0 + wr * 64 + i * 16 + quad * 4 + r;
#pragma unroll
            for (int j = 0; j < 4; j++) {
                const int c = col0 + wc * 64 + j * 16 + l15;
                dst[(size_t)row * D_MODEL + c] = acc[i][j][r];
            }
        }
    }
}

// out = P0 + P1 (fp32). (R9 lesson: atomicAdd combine costs +14us.)
__global__ __launch_bounds__(256) void add_out_kernel(
    const float* __restrict__ P, float* __restrict__ out)
{
    const float4* p0 = (const float4*)P;
    const float4* p1 = (const float4*)(P + 4096ull * 1024ull);
    float4* o = (float4*)out;
    const int base = (blockIdx.x * 256 + threadIdx.x) * 4;
#pragma unroll
    for (int j = 0; j < 4; j++) {
        float4 a = p0[base + j], b = p1[base + j];
        float4 r = {a.x + b.x, a.y + b.y, a.z + b.z, a.w + b.w};
        o[base + j] = r;
    }
}

// ---------------------------------------------------------------------------
// Flash attention v5 (R7-proven): QBLK=64, 4 waves, zigzag qt balance.
// T13 defer-rescale, cvt_pk P-pack, per-lane l partial, setprio around MFMA.
// LDS 40 KB -> 4 blocks/CU. (R8: QBLK=128 regressed; keep 4 blocks/CU.)
// ---------------------------------------------------------------------------
__global__ __launch_bounds__(256) void flash_attn_kernel(
    const unsigned short* __restrict__ Q,
    const unsigned short* __restrict__ K,
    const unsigned short* __restrict__ Vt,
    unsigned short* __restrict__ O)
{
    const int idx = blockIdx.x;
    const int bh = idx & 31;
    const int qt2 = idx >> 5;
    const int hi = qt2 >> 3, lo = qt2 & 7;
    const int qt = (hi == 0) ? lo : (hi == 1) ? 31 - lo : (hi == 2) ? lo + 8 : 23 - lo;

    const int tid = threadIdx.x;
    const int w = tid >> 6, lane = tid & 63;
    const int l15 = lane & 15, quad = lane >> 4;

    __shared__ unsigned short Ks[2][4096];
    __shared__ unsigned short Vs[2][4096];
    __shared__ unsigned short Ps[4][1024];

    bf16x8 qf[2];
    {
        const unsigned short* qrow =
            Q + ((size_t)bh * SEQ + qt * 64 + w * 16 + l15) * HEAD_DIM;
        qf[0] = *(const bf16x8*)(qrow + quad * 8);
        qf[1] = *(const bf16x8*)(qrow + 32 + quad * 8);
    }

    const f32x4 zero4 = {0.f, 0.f, 0.f, 0.f};
    f32x4 o_acc[4] = {zero4, zero4, zero4, zero4};
    float m_i = -1e30f, l_i = 0.f;

    auto stage = [&](int bf, int kt_t) {
        const int key0 = kt_t * 64;
#pragma unroll
        for (int i = 0; i < 2; i++) {
            const int f = w * 2 + i;
            const int ct = f >> 1, kh = f & 1;
            gload_lds16(K + ((size_t)bh * SEQ + key0 + ct * 16 + l15) * HEAD_DIM
                          + kh * 32 + quad * 8,
                        &Ks[bf][f * 512 + lane * 8]);
            gload_lds16(Vt + ((size_t)bh * HEAD_DIM + ct * 16 + l15) * SEQ
                           + key0 + kh * 32 + quad * 8,
                        &Vs[bf][f * 512 + lane * 8]);
        }
    };

    stage(0, 0);
    int buf = 0;

    const int qg = qt * 64 + w * 16 + l15;

    for (int kt = 0; kt <= qt; kt++) {
        __syncthreads();
        if (kt < qt) stage(buf ^ 1, kt + 1);

        f32x4 st[4] = {zero4, zero4, zero4, zero4};
        __builtin_amdgcn_s_setprio(1);
#pragma unroll
        for (int kh = 0; kh < 2; kh++) {
#pragma unroll
            for (int ct = 0; ct < 4; ct++) {
                bf16x8 kf = *(const bf16x8*)&Ks[buf][(ct * 2 + kh) * 512 + lane * 8];
                st[ct] = __builtin_amdgcn_mfma_f32_16x16x32_bf16(kf, qf[kh], st[ct], 0, 0, 0);
            }
        }
        __builtin_amdgcn_s_setprio(0);

        float mt = -1e30f;
        if (kt == qt) {
#pragma unroll
            for (int ct = 0; ct < 4; ct++) {
#pragma unroll
                for (int r = 0; r < 4; r++) {
                    const int kg = kt * 64 + ct * 16 + quad * 4 + r;
                    float v = (kg > qg) ? -1e30f : st[ct][r];
                    st[ct][r] = v;
                    mt = fmaxf(mt, v);
                }
            }
        } else {
#pragma unroll
            for (int ct = 0; ct < 4; ct++)
#pragma unroll
                for (int r = 0; r < 4; r++)
                    mt = fmaxf(mt, st[ct][r]);
        }
        mt = fmaxf(mt, __shfl_xor(mt, 16));
        mt = fmaxf(mt, __shfl_xor(mt, 32));

        float mn = m_i;
        if (!__all(mt <= m_i + 8.0f)) {
            mn = fmaxf(m_i, mt);
            const float alpha = __expf(m_i - mn);
            m_i = mn;
            l_i *= alpha;
            float ar[4];
#pragma unroll
            for (int r = 0; r < 4; r++)
                ar[r] = __shfl(alpha, (lane & 48) | (quad * 4 + r));
#pragma unroll
            for (int dt = 0; dt < 4; dt++)
#pragma unroll
                for (int r = 0; r < 4; r++)
                    o_acc[dt][r] *= ar[r];
        }

        float ls = 0.f;
#pragma unroll
        for (int ct = 0; ct < 4; ct++) {
            const float p0 = __expf(st[ct][0] - mn);
            const float p1 = __expf(st[ct][1] - mn);
            const float p2 = __expf(st[ct][2] - mn);
            const float p3 = __expf(st[ct][3] - mn);
            ls += (p0 + p1) + (p2 + p3);
            uint2 pk2;
            pk2.x = cvtpk_bf16(p0, p1);
            pk2.y = cvtpk_bf16(p2, p3);
            const int addr = (ct >> 1) * 512 + ((ct & 1) * 2 + (quad >> 1)) * 128
                           + l15 * 8 + (quad & 1) * 4;
            *(uint2*)&Ps[w][addr] = pk2;
        }
        l_i += ls;

        __builtin_amdgcn_s_setprio(1);
#pragma unroll
        for (int kh = 0; kh < 2; kh++) {
            bf16x8 pa = *(const bf16x8*)&Ps[w][kh * 512 + quad * 128 + l15 * 8];
#pragma unroll
            for (int dt = 0; dt < 4; dt++) {
                bf16x8 vf = *(const bf16x8*)&Vs[buf][(dt * 2 + kh) * 512 + lane * 8];
                o_acc[dt] = __builtin_amdgcn_mfma_f32_16x16x32_bf16(pa, vf, o_acc[dt], 0, 0, 0);
            }
        }
        __builtin_amdgcn_s_setprio(0);
        buf ^= 1;
    }

    l_i += __shfl_xor(l_i, 16);
    l_i += __shfl_xor(l_i, 32);
    const float linv = 1.0f / l_i;
    float lr[4];
#pragma unroll
    for (int r = 0; r < 4; r++)
        lr[r] = __shfl(linv, (lane & 48) | (quad * 4 + r));

    const int b = bh >> 4, h = bh & 15;
#pragma unroll
    for (int r = 0; r < 4; r++) {
        const int q = qt * 64 + w * 16 + quad * 4 + r;
        unsigned short* orow = O + ((size_t)b * SEQ + q) * D_MODEL + h * HEAD_DIM;
#pragma unroll
        for (int dt = 0; dt < 4; dt++)
            orow[dt * 16 + l15] = f2bf_hw(o_acc[dt][r] * lr[r]);
    }
}

// ---------------------------------------------------------------------------
extern "C" void kernel_launch(void* const* d_in, const int* in_sizes, int n_in,
                              void* d_out, int out_size, void* d_ws, size_t ws_size,
                              hipStream_t stream) {
    const float* x      = (const float*)d_in[0];
    const float* w_qkv  = (const float*)d_in[1];
    const float* w_proj = (const float*)d_in[2];
    float* out = (float*)d_out;

    unsigned short* Xb  = (unsigned short*)d_ws;          // 4M shorts
    unsigned short* Wqt = Xb  + (size_t)4 * 1024 * 1024;  // 3M
    unsigned short* Wpt = Wqt + (size_t)3 * 1024 * 1024;  // 1M
    unsigned short* Qb  = Wpt + (size_t)1 * 1024 * 1024;  // 4M
    unsigned short* Kb  = Qb  + (size_t)4 * 1024 * 1024;  // 4M
    unsigned short* Vb  = Kb  + (size_t)4 * 1024 * 1024;  // 4M (spacer)
    unsigned short* Vtb = Vb  + (size_t)4 * 1024 * 1024;  // 4M (written by gemm)
    unsigned short* Ob  = Vtb + (size_t)4 * 1024 * 1024;  // 4M  (56 MB total)

    // Split-K partials alias Qb..Vtb (32 MB, dead after flash).
    float* Pp = (float*)Qb;

    fused_convert_kernel<<<dim3(6144), 256, 0, stream>>>(
        x, Xb, w_qkv, Wqt, w_proj, Wpt);

    gemm_qkv_mfma<<<dim3(3 * D_MODEL / 256, BATCH * SEQ / 256), 512, 0, stream>>>(
        Xb, Wqt, Qb, Kb, Vtb);

    flash_attn_kernel<<<dim3(SEQ / 64 * BATCH * N_HEADS), 256, 0, stream>>>(
        Qb, Kb, Vtb, Ob);

    gemm_proj_splitk<<<dim3(D_MODEL / 128, BATCH * SEQ / 128, 2), 256, 0, stream>>>(
        Ob, Wpt, Pp);

    add_out_kernel<<<dim3(1024), 256, 0, stream>>>(Pp, out);
}

// Round 12
// 211.020 us; speedup vs baseline: 1.0093x; 1.0093x over previous
//
#include <hip/hip_runtime.h>
#include <cstdint>
#include <cstddef>

#define D_MODEL 1024
#define N_HEADS 16
#define HEAD_DIM 64
#define SEQ 2048
#define BATCH 2

typedef __attribute__((ext_vector_type(8))) short bf16x8;
typedef __attribute__((ext_vector_type(4))) float f32x4;

// Hardware bf16 convert (RNE): 1 VALU op per 2 elements.
__device__ __forceinline__ unsigned cvtpk_bf16(float lo, float hi) {
    unsigned r;
    asm("v_cvt_pk_bf16_f32 %0, %1, %2" : "=v"(r) : "v"(lo), "v"(hi));
    return r;
}
__device__ __forceinline__ unsigned short f2bf_hw(float f) {
    return (unsigned short)cvtpk_bf16(f, 0.f);
}

// async global->LDS, 16 B per lane; LDS dst must be wave-base + lane*16.
__device__ __forceinline__ void gload_lds16(const unsigned short* g, unsigned short* l) {
    __builtin_amdgcn_global_load_lds(
        (const __attribute__((address_space(1))) unsigned int*)g,
        (__attribute__((address_space(3))) unsigned int*)l, 16, 0, 0);
}

// s_waitcnt immediates (gfx9: vmcnt[3:0]|[15:14], expcnt[6:4], lgkmcnt[11:8])
#define WAITCNT_VM4 0x0F74   // vmcnt(4), expcnt/lgkmcnt = no-wait
#define WAITCNT_VM0 0x0F70   // vmcnt(0)

// ---------------------------------------------------------------------------
// Fused converts: x->bf16 | w_qkv->Wqt (permuted transpose, Q pre-scaled) |
// w_proj->Wpt.
// ---------------------------------------------------------------------------
__global__ __launch_bounds__(256) void fused_convert_kernel(
    const float* __restrict__ X, unsigned short* __restrict__ Xb,
    const float* __restrict__ Wq, unsigned short* __restrict__ Wqt,
    const float* __restrict__ Wp, unsigned short* __restrict__ Wpt)
{
    const int blk = blockIdx.x;
    const int tid = threadIdx.x;
    __shared__ float t[32][33];

    if (blk < 2048) {
        const int idx = blk * 256 + tid;
        const float4* src = (const float4*)X;
        float4 v0 = src[idx * 2], v1 = src[idx * 2 + 1];
        uint4 o;
        o.x = cvtpk_bf16(v0.x, v0.y);
        o.y = cvtpk_bf16(v0.z, v0.w);
        o.z = cvtpk_bf16(v1.x, v1.y);
        o.w = cvtpk_bf16(v1.z, v1.w);
        ((uint4*)Xb)[idx] = o;
    } else if (blk < 5120) {
        const int bb = blk - 2048;
        const int c0 = (bb % 96) * 32, r0 = (bb / 96) * 32;
        const int a = tid & 31, b = tid >> 5;
#pragma unroll
        for (int i = 0; i < 32; i += 8)
            t[b + i][a] = Wq[(size_t)(r0 + b + i) * (3 * D_MODEL) + c0 + a];
        __syncthreads();
#pragma unroll
        for (int i = 0; i < 32; i += 8) {
            const int c = c0 + b + i;
            const int which = c % 3;
            const int np = which * 1024 + c / 3;   // which*1024 + h*64 + d
            const float s = (which == 0) ? 0.125f : 1.0f;
            Wqt[(size_t)np * D_MODEL + r0 + a] = f2bf_hw(t[a][b + i] * s);
        }
    } else {
        const int bb = blk - 5120;
        const int c0 = (bb % 32) * 32, r0 = (bb / 32) * 32;
        const int a = tid & 31, b = tid >> 5;
#pragma unroll
        for (int i = 0; i < 32; i += 8)
            t[b + i][a] = Wp[(size_t)(r0 + b + i) * D_MODEL + c0 + a];
        __syncthreads();
#pragma unroll
        for (int i = 0; i < 32; i += 8)
            Wpt[(size_t)(c0 + b + i) * D_MODEL + r0 + a] = f2bf_hw(t[a][b + i]);
    }
}

// ---------------------------------------------------------------------------
// Pipelined GEMM core (R2/R4-proven): 128x128 tile, BK=32, triple-buffer LDS,
// stage depth 2, raw s_barrier + counted vmcnt(4) (never drains mid-loop).
// setprio around MFMA cluster (R4 vs R6 A/B: positive in this
// 3-independent-barrier-groups/CU regime). LDS 48 KB -> 3 blocks/CU.
// R11 lesson: deeper pipelines (256^2, counted vmcnt(8), 32 MFMA/barrier)
// land at the SAME ~56us -- the plateau is shape-structural (K=1024), not
// schedule-depth-limited.
// ---------------------------------------------------------------------------
#define GEMM_PIPE3_BODY(A_, B_, KBASE, NITER, BX_, BY_)                        \
    const int tid = threadIdx.x;                                               \
    const int w = tid >> 6, lane = tid & 63;                                   \
    const int l15 = lane & 15, quad = lane >> 4;                               \
    const int wr = w >> 1, wc = w & 1;                                         \
    const int row0 = (BY_) * 128, col0 = (BX_) * 128;                          \
    __shared__ unsigned short As[3][4096];                                     \
    __shared__ unsigned short Bs[3][4096];                                     \
    const f32x4 zero4 = {0.f, 0.f, 0.f, 0.f};                                  \
    f32x4 acc[4][4];                                                           \
    _Pragma("unroll") for (int i = 0; i < 4; i++)                              \
        _Pragma("unroll") for (int j = 0; j < 4; j++) acc[i][j] = zero4;       \
    auto stage_ = [&](int sb_, int kt_) {                                      \
        const int k0 = (KBASE) + kt_ * 32 + quad * 8;                          \
        _Pragma("unroll") for (int i = 0; i < 2; i++) {                        \
            const int f = w * 2 + i;                                           \
            gload_lds16((A_) + (size_t)(row0 + f * 16 + l15) * D_MODEL + k0,   \
                        &As[sb_][f * 512 + lane * 8]);                         \
            gload_lds16((B_) + (size_t)(col0 + f * 16 + l15) * D_MODEL + k0,   \
                        &Bs[sb_][f * 512 + lane * 8]);                         \
        }                                                                      \
    };                                                                         \
    stage_(0, 0);                                                              \
    stage_(1, 1);                                                              \
    int sb = 0;                                                                \
    for (int kt = 0; kt < (NITER); kt++) {                                     \
        if (kt < (NITER) - 1) {                                                \
            __builtin_amdgcn_s_waitcnt(WAITCNT_VM4);                           \
            __builtin_amdgcn_s_barrier();                                      \
            if (kt + 2 < (NITER)) stage_((sb + 2 > 2) ? sb - 1 : sb + 2, kt + 2); \
        } else {                                                               \
            __builtin_amdgcn_s_waitcnt(WAITCNT_VM0);                           \
            __builtin_amdgcn_s_barrier();                                      \
        }                                                                      \
        bf16x8 af[4], bfr[4];                                                  \
        _Pragma("unroll") for (int i = 0; i < 4; i++)                          \
            af[i] = *(const bf16x8*)&As[sb][(wr * 4 + i) * 512 + lane * 8];    \
        _Pragma("unroll") for (int j = 0; j < 4; j++)                          \
            bfr[j] = *(const bf16x8*)&Bs[sb][(wc * 4 + j) * 512 + lane * 8];   \
        __builtin_amdgcn_s_setprio(1);                                         \
        _Pragma("unroll") for (int i = 0; i < 4; i++)                          \
            _Pragma("unroll") for (int j = 0; j < 4; j++)                      \
                acc[i][j] = __builtin_amdgcn_mfma_f32_16x16x32_bf16(           \
                    af[i], bfr[j], acc[i][j], 0, 0, 0);                        \
        __builtin_amdgcn_s_setprio(0);                                         \
        sb = (sb == 2) ? 0 : sb + 1;                                           \
    }

// GEMM1: Xb @ Wqt^T -> Q/K bf16 [bh][n][d]; V written directly transposed to
// Vt[bh][d][n] via LDS-transposed epilogue (R7-proven: 256B-contiguous runs).
// T1 XCD swizzle: 96/XCD as 12(bx) x 8(by) rect -> ~5MB/XCD working set.
__global__ __launch_bounds__(256) void gemm_qkv_mfma(
    const unsigned short* __restrict__ A, const unsigned short* __restrict__ B,
    unsigned short* __restrict__ Q, unsigned short* __restrict__ Kq,
    unsigned short* __restrict__ Vt)
{
    const int lin = blockIdx.x + 24 * blockIdx.y;   // 0..767, %8 = XCD
    const int xcd = lin & 7, t = lin >> 3;          // t: 0..95
    const int bx = (xcd & 1) * 12 + t % 12;         // 0..23
    const int by = (xcd >> 1) * 8 + t / 12;         // 0..31
    GEMM_PIPE3_BODY(A, B, 0, 32, bx, by)
    const int nbase = col0 + wc * 64;              // wave-uniform, mult of 64
    const int which = col0 >> 10;                  // 0:Q 1:K 2:V (BLOCK-uniform)
    if (which < 2) {
        unsigned short* const dst = (which == 0) ? Q : Kq;
#pragma unroll
        for (int i = 0; i < 4; i++) {
            const int rowb = row0 + wr * 64 + i * 16 + quad * 4;
            const int bb = rowb >> 11, n = rowb & (SEQ - 1);
#pragma unroll
            for (int rp = 0; rp < 2; rp++) {
#pragma unroll
                for (int j = 0; j < 4; j++) {
                    const unsigned u = cvtpk_bf16(acc[i][j][2 * rp], acc[i][j][2 * rp + 1]);
                    const int idx = (nbase + j * 16 + l15) & 1023;  // h*64+d
                    const int h = idx >> 6, dd = idx & 63;
                    unsigned short* p =
                        dst + (((size_t)(bb * N_HEADS + h)) * SEQ + n + 2 * rp) * HEAD_DIM + dd;
                    p[0] = (unsigned short)u;
                    p[HEAD_DIM] = (unsigned short)(u >> 16);
                }
            }
        }
    } else {
        // V epilogue: LDS transpose in two 64-col halves (dead As space).
        unsigned short* vt = &As[0][0];              // 64*136*2 = 17408B
        const int n0 = row0 & (SEQ - 1);
        const int bb = row0 >> 11;
        const int vbase = col0 & 1023;               // mult of 128: h*64+d base
        __syncthreads();                             // K-loop LDS reads done
#pragma unroll
        for (int half = 0; half < 2; half++) {
            if (wc == half) {
#pragma unroll
                for (int i = 0; i < 4; i++) {
                    const int nl = wr * 64 + i * 16 + quad * 4;
#pragma unroll
                    for (int rp = 0; rp < 2; rp++) {
#pragma unroll
                        for (int j = 0; j < 4; j++) {
                            const unsigned u =
                                cvtpk_bf16(acc[i][j][2 * rp], acc[i][j][2 * rp + 1]);
                            const int c_loc = j * 16 + l15;          // 0..63
                            *(unsigned*)&vt[c_loc * 136 + nl + 2 * rp] = u;
                        }
                    }
                }
            }
            __syncthreads();
#pragma unroll
            for (int pass = 0; pass < 4; pass++) {
                const int c_loc = pass * 16 + (tid >> 4);            // 0..63
                const int t16 = tid & 15;
                const uint4 v = *(const uint4*)&vt[c_loc * 136 + t16 * 8];
                const int vc = vbase + half * 64 + c_loc;            // h*64+d
                *(uint4*)&Vt[((size_t)(bb * N_HEADS + (vc >> 6)) * HEAD_DIM
                              + (vc & 63)) * SEQ + n0 + t16 * 8] = v;
            }
            if (half == 0) __syncthreads();          // before 2nd-half writes
        }
    }
}

// GEMM2: SPLIT-K=2, pipelined. Grid (8, 32, 2). K=512/block, NITER=16.
// P-buffer + add_out combine (R9 lesson: atomicAdd combine costs +14us --
// per-lane L2 RMW transactions dwarf the 80MB traffic saved).
// T1 XCD swizzle per z-slice: 32/XCD as 4(bx) x 8(by) rectangle.
__global__ __launch_bounds__(256) void gemm_proj_splitk(
    const unsigned short* __restrict__ A, const unsigned short* __restrict__ B,
    float* __restrict__ P)
{
    const int lin = blockIdx.x + 8 * blockIdx.y;    // 0..255, %8 = XCD
    const int xcd = lin & 7, t = lin >> 3;          // t: 0..31
    const int bx = (xcd & 1) * 4 + t % 4;           // 0..7
    const int by = (xcd >> 1) * 8 + t / 4;          // 0..31
    const int kbase = blockIdx.z * 512;
    GEMM_PIPE3_BODY(A, B, kbase, 16, bx, by)
    float* const dst = P + (size_t)blockIdx.z * (4096ull * 1024ull);
#pragma unroll
    for (int i = 0; i < 4; i++) {
#pragma unroll
        for (int r = 0; r < 4; r++) {
            const int row = row0 + wr * 64 + i * 16 + quad * 4 + r;
#pragma unroll
            for (int j = 0; j < 4; j++) {
                const int c = col0 + wc * 64 + j * 16 + l15;
                dst[(size_t)row * D_MODEL + c] = acc[i][j][r];
            }
        }
    }
}

// out = P0 + P1 (fp32). 4M floats = 1M float4; 1024 blocks x 256 thr x 4.
__global__ __launch_bounds__(256) void add_out_kernel(
    const float* __restrict__ P, float* __restrict__ out)
{
    const float4* p0 = (const float4*)P;
    const float4* p1 = (const float4*)(P + 4096ull * 1024ull);
    float4* o = (float4*)out;
    const int base = (blockIdx.x * 256 + threadIdx.x) * 4;
#pragma unroll
    for (int j = 0; j < 4; j++) {
        float4 a = p0[base + j], b = p1[base + j];
        float4 r = {a.x + b.x, a.y + b.y, a.z + b.z, a.w + b.w};
        o[base + j] = r;
    }
}

// ---------------------------------------------------------------------------
// Flash attention v5 (R7-proven): QBLK=64, 4 waves, zigzag qt balance.
// T13 defer-rescale, cvt_pk P-pack, per-lane l partial, setprio around MFMA.
// LDS 40 KB -> 4 blocks/CU. (R8: QBLK=128 regressed; keep 4 blocks/CU.)
// ---------------------------------------------------------------------------
__global__ __launch_bounds__(256) void flash_attn_kernel(
    const unsigned short* __restrict__ Q,
    const unsigned short* __restrict__ K,
    const unsigned short* __restrict__ Vt,
    unsigned short* __restrict__ O)
{
    const int idx = blockIdx.x;
    const int bh = idx & 31;
    const int qt2 = idx >> 5;
    const int hi = qt2 >> 3, lo = qt2 & 7;
    const int qt = (hi == 0) ? lo : (hi == 1) ? 31 - lo : (hi == 2) ? lo + 8 : 23 - lo;

    const int tid = threadIdx.x;
    const int w = tid >> 6, lane = tid & 63;
    const int l15 = lane & 15, quad = lane >> 4;

    __shared__ unsigned short Ks[2][4096];
    __shared__ unsigned short Vs[2][4096];
    __shared__ unsigned short Ps[4][1024];

    bf16x8 qf[2];
    {
        const unsigned short* qrow =
            Q + ((size_t)bh * SEQ + qt * 64 + w * 16 + l15) * HEAD_DIM;
        qf[0] = *(const bf16x8*)(qrow + quad * 8);
        qf[1] = *(const bf16x8*)(qrow + 32 + quad * 8);
    }

    const f32x4 zero4 = {0.f, 0.f, 0.f, 0.f};
    f32x4 o_acc[4] = {zero4, zero4, zero4, zero4};
    float m_i = -1e30f, l_i = 0.f;

    auto stage = [&](int bf, int kt_t) {
        const int key0 = kt_t * 64;
#pragma unroll
        for (int i = 0; i < 2; i++) {
            const int f = w * 2 + i;
            const int ct = f >> 1, kh = f & 1;
            gload_lds16(K + ((size_t)bh * SEQ + key0 + ct * 16 + l15) * HEAD_DIM
                          + kh * 32 + quad * 8,
                        &Ks[bf][f * 512 + lane * 8]);
            gload_lds16(Vt + ((size_t)bh * HEAD_DIM + ct * 16 + l15) * SEQ
                           + key0 + kh * 32 + quad * 8,
                        &Vs[bf][f * 512 + lane * 8]);
        }
    };

    stage(0, 0);
    int buf = 0;

    const int qg = qt * 64 + w * 16 + l15;

    for (int kt = 0; kt <= qt; kt++) {
        __syncthreads();
        if (kt < qt) stage(buf ^ 1, kt + 1);

        f32x4 st[4] = {zero4, zero4, zero4, zero4};
        __builtin_amdgcn_s_setprio(1);
#pragma unroll
        for (int kh = 0; kh < 2; kh++) {
#pragma unroll
            for (int ct = 0; ct < 4; ct++) {
                bf16x8 kf = *(const bf16x8*)&Ks[buf][(ct * 2 + kh) * 512 + lane * 8];
                st[ct] = __builtin_amdgcn_mfma_f32_16x16x32_bf16(kf, qf[kh], st[ct], 0, 0, 0);
            }
        }
        __builtin_amdgcn_s_setprio(0);

        float mt = -1e30f;
        if (kt == qt) {
#pragma unroll
            for (int ct = 0; ct < 4; ct++) {
#pragma unroll
                for (int r = 0; r < 4; r++) {
                    const int kg = kt * 64 + ct * 16 + quad * 4 + r;
                    float v = (kg > qg) ? -1e30f : st[ct][r];
                    st[ct][r] = v;
                    mt = fmaxf(mt, v);
                }
            }
        } else {
#pragma unroll
            for (int ct = 0; ct < 4; ct++)
#pragma unroll
                for (int r = 0; r < 4; r++)
                    mt = fmaxf(mt, st[ct][r]);
        }
        mt = fmaxf(mt, __shfl_xor(mt, 16));
        mt = fmaxf(mt, __shfl_xor(mt, 32));

        float mn = m_i;
        if (!__all(mt <= m_i + 8.0f)) {
            mn = fmaxf(m_i, mt);
            const float alpha = __expf(m_i - mn);
            m_i = mn;
            l_i *= alpha;
            float ar[4];
#pragma unroll
            for (int r = 0; r < 4; r++)
                ar[r] = __shfl(alpha, (lane & 48) | (quad * 4 + r));
#pragma unroll
            for (int dt = 0; dt < 4; dt++)
#pragma unroll
                for (int r = 0; r < 4; r++)
                    o_acc[dt][r] *= ar[r];
        }

        float ls = 0.f;
#pragma unroll
        for (int ct = 0; ct < 4; ct++) {
            const float p0 = __expf(st[ct][0] - mn);
            const float p1 = __expf(st[ct][1] - mn);
            const float p2 = __expf(st[ct][2] - mn);
            const float p3 = __expf(st[ct][3] - mn);
            ls += (p0 + p1) + (p2 + p3);
            uint2 pk2;
            pk2.x = cvtpk_bf16(p0, p1);
            pk2.y = cvtpk_bf16(p2, p3);
            const int addr = (ct >> 1) * 512 + ((ct & 1) * 2 + (quad >> 1)) * 128
                           + l15 * 8 + (quad & 1) * 4;
            *(uint2*)&Ps[w][addr] = pk2;
        }
        l_i += ls;

        __builtin_amdgcn_s_setprio(1);
#pragma unroll
        for (int kh = 0; kh < 2; kh++) {
            bf16x8 pa = *(const bf16x8*)&Ps[w][kh * 512 + quad * 128 + l15 * 8];
#pragma unroll
            for (int dt = 0; dt < 4; dt++) {
                bf16x8 vf = *(const bf16x8*)&Vs[buf][(dt * 2 + kh) * 512 + lane * 8];
                o_acc[dt] = __builtin_amdgcn_mfma_f32_16x16x32_bf16(pa, vf, o_acc[dt], 0, 0, 0);
            }
        }
        __builtin_amdgcn_s_setprio(0);
        buf ^= 1;
    }

    l_i += __shfl_xor(l_i, 16);
    l_i += __shfl_xor(l_i, 32);
    const float linv = 1.0f / l_i;
    float lr[4];
#pragma unroll
    for (int r = 0; r < 4; r++)
        lr[r] = __shfl(linv, (lane & 48) | (quad * 4 + r));

    const int b = bh >> 4, h = bh & 15;
#pragma unroll
    for (int r = 0; r < 4; r++) {
        const int q = qt * 64 + w * 16 + quad * 4 + r;
        unsigned short* orow = O + ((size_t)b * SEQ + q) * D_MODEL + h * HEAD_DIM;
#pragma unroll
        for (int dt = 0; dt < 4; dt++)
            orow[dt * 16 + l15] = f2bf_hw(o_acc[dt][r] * lr[r]);
    }
}

// ---------------------------------------------------------------------------
extern "C" void kernel_launch(void* const* d_in, const int* in_sizes, int n_in,
                              void* d_out, int out_size, void* d_ws, size_t ws_size,
                              hipStream_t stream) {
    const float* x      = (const float*)d_in[0];
    const float* w_qkv  = (const float*)d_in[1];
    const float* w_proj = (const float*)d_in[2];
    float* out = (float*)d_out;

    unsigned short* Xb  = (unsigned short*)d_ws;          // 4M shorts
    unsigned short* Wqt = Xb  + (size_t)4 * 1024 * 1024;  // 3M
    unsigned short* Wpt = Wqt + (size_t)3 * 1024 * 1024;  // 1M
    unsigned short* Qb  = Wpt + (size_t)1 * 1024 * 1024;  // 4M
    unsigned short* Kb  = Qb  + (size_t)4 * 1024 * 1024;  // 4M
    unsigned short* Vb  = Kb  + (size_t)4 * 1024 * 1024;  // 4M (spacer)
    unsigned short* Vtb = Vb  + (size_t)4 * 1024 * 1024;  // 4M (written by gemm)
    unsigned short* Ob  = Vtb + (size_t)4 * 1024 * 1024;  // 4M  (56 MB total)

    // Split-K partials alias Qb..Vtb (32 MB, dead after flash).
    float* Pp = (float*)Qb;

    fused_convert_kernel<<<dim3(6144), 256, 0, stream>>>(
        x, Xb, w_qkv, Wqt, w_proj, Wpt);

    gemm_qkv_mfma<<<dim3(3 * D_MODEL / 128, BATCH * SEQ / 128), 256, 0, stream>>>(
        Xb, Wqt, Qb, Kb, Vtb);

    flash_attn_kernel<<<dim3(SEQ / 64 * BATCH * N_HEADS), 256, 0, stream>>>(
        Qb, Kb, Vtb, Ob);

    gemm_proj_splitk<<<dim3(D_MODEL / 128, BATCH * SEQ / 128, 2), 256, 0, stream>>>(
        Ob, Wpt, Pp);

    add_out_kernel<<<dim3(1024), 256, 0, stream>>>(Pp, out);
}

// Round 13
// 200.364 us; speedup vs baseline: 1.0629x; 1.0532x over previous
//
#include <hip/hip_runtime.h>
#include <cstdint>
#include <cstddef>

#define D_MODEL 1024
#define N_HEADS 16
#define HEAD_DIM 64
#define SEQ 2048
#define BATCH 2

typedef __attribute__((ext_vector_type(8))) short bf16x8;
typedef __attribute__((ext_vector_type(4))) float f32x4;

// Hardware bf16 convert (RNE): 1 VALU op per 2 elements.
__device__ __forceinline__ unsigned cvtpk_bf16(float lo, float hi) {
    unsigned r;
    asm("v_cvt_pk_bf16_f32 %0, %1, %2" : "=v"(r) : "v"(lo), "v"(hi));
    return r;
}
__device__ __forceinline__ unsigned short f2bf_hw(float f) {
    return (unsigned short)cvtpk_bf16(f, 0.f);
}

// async global->LDS, 16 B per lane; LDS dst must be wave-base + lane*16.
__device__ __forceinline__ void gload_lds16(const unsigned short* g, unsigned short* l) {
    __builtin_amdgcn_global_load_lds(
        (const __attribute__((address_space(1))) unsigned int*)g,
        (__attribute__((address_space(3))) unsigned int*)l, 16, 0, 0);
}

// s_waitcnt immediates (gfx9: vmcnt[3:0]|[15:14], expcnt[6:4], lgkmcnt[11:8])
#define WAITCNT_VM4 0x0F74   // vmcnt(4), expcnt/lgkmcnt = no-wait
#define WAITCNT_VM0 0x0F70   // vmcnt(0)

// ---------------------------------------------------------------------------
// Fused converts: x->bf16 | w_qkv->Wqt (permuted transpose, Q pre-scaled) |
// w_proj->Wpt.
// ---------------------------------------------------------------------------
__global__ __launch_bounds__(256) void fused_convert_kernel(
    const float* __restrict__ X, unsigned short* __restrict__ Xb,
    const float* __restrict__ Wq, unsigned short* __restrict__ Wqt,
    const float* __restrict__ Wp, unsigned short* __restrict__ Wpt)
{
    const int blk = blockIdx.x;
    const int tid = threadIdx.x;
    __shared__ float t[32][33];

    if (blk < 2048) {
        const int idx = blk * 256 + tid;
        const float4* src = (const float4*)X;
        float4 v0 = src[idx * 2], v1 = src[idx * 2 + 1];
        uint4 o;
        o.x = cvtpk_bf16(v0.x, v0.y);
        o.y = cvtpk_bf16(v0.z, v0.w);
        o.z = cvtpk_bf16(v1.x, v1.y);
        o.w = cvtpk_bf16(v1.z, v1.w);
        ((uint4*)Xb)[idx] = o;
    } else if (blk < 5120) {
        const int bb = blk - 2048;
        const int c0 = (bb % 96) * 32, r0 = (bb / 96) * 32;
        const int a = tid & 31, b = tid >> 5;
#pragma unroll
        for (int i = 0; i < 32; i += 8)
            t[b + i][a] = Wq[(size_t)(r0 + b + i) * (3 * D_MODEL) + c0 + a];
        __syncthreads();
#pragma unroll
        for (int i = 0; i < 32; i += 8) {
            const int c = c0 + b + i;
            const int which = c % 3;
            const int np = which * 1024 + c / 3;   // which*1024 + h*64 + d
            const float s = (which == 0) ? 0.125f : 1.0f;
            Wqt[(size_t)np * D_MODEL + r0 + a] = f2bf_hw(t[a][b + i] * s);
        }
    } else {
        const int bb = blk - 5120;
        const int c0 = (bb % 32) * 32, r0 = (bb / 32) * 32;
        const int a = tid & 31, b = tid >> 5;
#pragma unroll
        for (int i = 0; i < 32; i += 8)
            t[b + i][a] = Wp[(size_t)(r0 + b + i) * D_MODEL + c0 + a];
        __syncthreads();
#pragma unroll
        for (int i = 0; i < 32; i += 8)
            Wpt[(size_t)(c0 + b + i) * D_MODEL + r0 + a] = f2bf_hw(t[a][b + i]);
    }
}

// ---------------------------------------------------------------------------
// Pipelined GEMM core (R2/R4-proven): 128x128 tile, BK=32, triple-buffer LDS,
// stage depth 2, raw s_barrier + counted vmcnt(4) (never drains mid-loop).
// setprio around MFMA cluster. LDS 48 KB -> 3 blocks/CU.
// ---------------------------------------------------------------------------
#define GEMM_PIPE3_BODY(A_, B_, KBASE, NITER, BX_, BY_)                        \
    const int tid = threadIdx.x;                                               \
    const int w = tid >> 6, lane = tid & 63;                                   \
    const int l15 = lane & 15, quad = lane >> 4;                               \
    const int wr = w >> 1, wc = w & 1;                                         \
    const int row0 = (BY_) * 128, col0 = (BX_) * 128;                          \
    __shared__ unsigned short As[3][4096];                                     \
    __shared__ unsigned short Bs[3][4096];                                     \
    const f32x4 zero4 = {0.f, 0.f, 0.f, 0.f};                                  \
    f32x4 acc[4][4];                                                           \
    _Pragma("unroll") for (int i = 0; i < 4; i++)                              \
        _Pragma("unroll") for (int j = 0; j < 4; j++) acc[i][j] = zero4;       \
    auto stage_ = [&](int sb_, int kt_) {                                      \
        const int k0 = (KBASE) + kt_ * 32 + quad * 8;                          \
        _Pragma("unroll") for (int i = 0; i < 2; i++) {                        \
            const int f = w * 2 + i;                                           \
            gload_lds16((A_) + (size_t)(row0 + f * 16 + l15) * D_MODEL + k0,   \
                        &As[sb_][f * 512 + lane * 8]);                         \
            gload_lds16((B_) + (size_t)(col0 + f * 16 + l15) * D_MODEL + k0,   \
                        &Bs[sb_][f * 512 + lane * 8]);                         \
        }                                                                      \
    };                                                                         \
    stage_(0, 0);                                                              \
    stage_(1, 1);                                                              \
    int sb = 0;                                                                \
    for (int kt = 0; kt < (NITER); kt++) {                                     \
        if (kt < (NITER) - 1) {                                                \
            __builtin_amdgcn_s_waitcnt(WAITCNT_VM4);                           \
            __builtin_amdgcn_s_barrier();                                      \
            if (kt + 2 < (NITER)) stage_((sb + 2 > 2) ? sb - 1 : sb + 2, kt + 2); \
        } else {                                                               \
            __builtin_amdgcn_s_waitcnt(WAITCNT_VM0);                           \
            __builtin_amdgcn_s_barrier();                                      \
        }                                                                      \
        bf16x8 af[4], bfr[4];                                                  \
        _Pragma("unroll") for (int i = 0; i < 4; i++)                          \
            af[i] = *(const bf16x8*)&As[sb][(wr * 4 + i) * 512 + lane * 8];    \
        _Pragma("unroll") for (int j = 0; j < 4; j++)                          \
            bfr[j] = *(const bf16x8*)&Bs[sb][(wc * 4 + j) * 512 + lane * 8];   \
        __builtin_amdgcn_s_setprio(1);                                         \
        _Pragma("unroll") for (int i = 0; i < 4; i++)                          \
            _Pragma("unroll") for (int j = 0; j < 4; j++)                      \
                acc[i][j] = __builtin_amdgcn_mfma_f32_16x16x32_bf16(           \
                    af[i], bfr[j], acc[i][j], 0, 0, 0);                        \
        __builtin_amdgcn_s_setprio(0);                                         \
        sb = (sb == 2) ? 0 : sb + 1;                                           \
    }

// GEMM1: Xb @ Wqt^T -> Q/K bf16 [bh][n][d]; V written directly transposed to
// Vt[bh][d][n] via LDS-transposed epilogue (R7-proven: 256B-contiguous runs).
// T1 XCD swizzle: 96/XCD as 12(bx) x 8(by) rect -> ~5MB/XCD working set.
__global__ __launch_bounds__(256) void gemm_qkv_mfma(
    const unsigned short* __restrict__ A, const unsigned short* __restrict__ B,
    unsigned short* __restrict__ Q, unsigned short* __restrict__ Kq,
    unsigned short* __restrict__ Vt)
{
    const int lin = blockIdx.x + 24 * blockIdx.y;   // 0..767, %8 = XCD
    const int xcd = lin & 7, t = lin >> 3;          // t: 0..95
    const int bx = (xcd & 1) * 12 + t % 12;         // 0..23
    const int by = (xcd >> 1) * 8 + t / 12;         // 0..31
    GEMM_PIPE3_BODY(A, B, 0, 32, bx, by)
    const int nbase = col0 + wc * 64;              // wave-uniform, mult of 64
    const int which = col0 >> 10;                  // 0:Q 1:K 2:V (BLOCK-uniform)
    if (which < 2) {
        unsigned short* const dst = (which == 0) ? Q : Kq;
#pragma unroll
        for (int i = 0; i < 4; i++) {
            const int rowb = row0 + wr * 64 + i * 16 + quad * 4;
            const int bb = rowb >> 11, n = rowb & (SEQ - 1);
#pragma unroll
            for (int rp = 0; rp < 2; rp++) {
#pragma unroll
                for (int j = 0; j < 4; j++) {
                    const unsigned u = cvtpk_bf16(acc[i][j][2 * rp], acc[i][j][2 * rp + 1]);
                    const int idx = (nbase + j * 16 + l15) & 1023;  // h*64+d
                    const int h = idx >> 6, dd = idx & 63;
                    unsigned short* p =
                        dst + (((size_t)(bb * N_HEADS + h)) * SEQ + n + 2 * rp) * HEAD_DIM + dd;
                    p[0] = (unsigned short)u;
                    p[HEAD_DIM] = (unsigned short)(u >> 16);
                }
            }
        }
    } else {
        // V epilogue: LDS transpose in two 64-col halves (dead As space).
        unsigned short* vt = &As[0][0];              // 64*136*2 = 17408B
        const int n0 = row0 & (SEQ - 1);
        const int bb = row0 >> 11;
        const int vbase = col0 & 1023;               // mult of 128: h*64+d base
        __syncthreads();                             // K-loop LDS reads done
#pragma unroll
        for (int half = 0; half < 2; half++) {
            if (wc == half) {
#pragma unroll
                for (int i = 0; i < 4; i++) {
                    const int nl = wr * 64 + i * 16 + quad * 4;
#pragma unroll
                    for (int rp = 0; rp < 2; rp++) {
#pragma unroll
                        for (int j = 0; j < 4; j++) {
                            const unsigned u =
                                cvtpk_bf16(acc[i][j][2 * rp], acc[i][j][2 * rp + 1]);
                            const int c_loc = j * 16 + l15;          // 0..63
                            *(unsigned*)&vt[c_loc * 136 + nl + 2 * rp] = u;
                        }
                    }
                }
            }
            __syncthreads();
#pragma unroll
            for (int pass = 0; pass < 4; pass++) {
                const int c_loc = pass * 16 + (tid >> 4);            // 0..63
                const int t16 = tid & 15;
                const uint4 v = *(const uint4*)&vt[c_loc * 136 + t16 * 8];
                const int vc = vbase + half * 64 + c_loc;            // h*64+d
                *(uint4*)&Vt[((size_t)(bb * N_HEADS + (vc >> 6)) * HEAD_DIM
                              + (vc & 63)) * SEQ + n0 + t16 * 8] = v;
            }
            if (half == 0) __syncthreads();          // before 2nd-half writes
        }
    }
}

// ---------------------------------------------------------------------------
// GEMM2 fused: INTRA-BLOCK split-K=2. 512 threads: waves 0-3 run PIPE3 on
// K[0:512], waves 4-7 on K[512:1024], each with its OWN triple-buffered LDS
// pipeline (2 x 48KB = 96KB -> 1 block/CU). Barriers are shared but both
// halves execute the identical cadence. After the K-loop, half-1 waves push
// accs through LDS (slot-major layout: lane-consecutive float4 -> conflict-
// free b128) in 2 phases; half-0 adds and writes f32 out DIRECTLY.
// Eliminates: add_out dispatch (+gap) and 80 MB of P round-trip traffic.
// R9 lesson honored: stores not atomics. R11 evidence: 8-wave/1-block-per-CU
// pipelined structure matches PIPE3 per-work throughput at this tile size.
// Grid (8, 32) = 256 blocks; XCD swizzle 32/XCD as 4(bx) x 8(by) rect.
// ---------------------------------------------------------------------------
__global__ __launch_bounds__(512, 2) void gemm_proj_fused(
    const unsigned short* __restrict__ A, const unsigned short* __restrict__ B,
    float* __restrict__ Outp)
{
    const int lin = blockIdx.x + 8 * blockIdx.y;    // 0..255, %8 = XCD
    const int xcd = lin & 7, t = lin >> 3;          // t: 0..31
    const int bx = (xcd & 1) * 4 + t % 4;           // 0..7
    const int by = (xcd >> 1) * 8 + t / 4;          // 0..31

    const int tid = threadIdx.x;
    const int w = tid >> 6, lane = tid & 63;        // w: 0..7
    const int half = w >> 2, wl = w & 3;            // K-half, wave-in-half
    const int l15 = lane & 15, quad = lane >> 4;
    const int wr = wl >> 1, wc = wl & 1;
    const int row0 = by * 128, col0 = bx * 128;
    const int kbase = half * 512;

    __shared__ unsigned short As[2][3][4096];       // [half][buf]
    __shared__ unsigned short Bs[2][3][4096];

    const f32x4 zero4 = {0.f, 0.f, 0.f, 0.f};
    f32x4 acc[4][4];
#pragma unroll
    for (int i = 0; i < 4; i++)
#pragma unroll
        for (int j = 0; j < 4; j++) acc[i][j] = zero4;

    auto stage_ = [&](int sb_, int kt_) {
        const int k0 = kbase + kt_ * 32 + quad * 8;
#pragma unroll
        for (int i = 0; i < 2; i++) {
            const int f = wl * 2 + i;
            gload_lds16(A + (size_t)(row0 + f * 16 + l15) * D_MODEL + k0,
                        &As[half][sb_][f * 512 + lane * 8]);
            gload_lds16(B + (size_t)(col0 + f * 16 + l15) * D_MODEL + k0,
                        &Bs[half][sb_][f * 512 + lane * 8]);
        }
    };

    stage_(0, 0);
    stage_(1, 1);
    int sb = 0;
    for (int kt = 0; kt < 16; kt++) {
        if (kt < 15) {
            __builtin_amdgcn_s_waitcnt(WAITCNT_VM4);
            __builtin_amdgcn_s_barrier();
            if (kt + 2 < 16) stage_((sb + 2 > 2) ? sb - 1 : sb + 2, kt + 2);
        } else {
            __builtin_amdgcn_s_waitcnt(WAITCNT_VM0);
            __builtin_amdgcn_s_barrier();
        }
        bf16x8 af[4], bfr[4];
#pragma unroll
        for (int i = 0; i < 4; i++)
            af[i] = *(const bf16x8*)&As[half][sb][(wr * 4 + i) * 512 + lane * 8];
#pragma unroll
        for (int j = 0; j < 4; j++)
            bfr[j] = *(const bf16x8*)&Bs[half][sb][(wc * 4 + j) * 512 + lane * 8];
        __builtin_amdgcn_s_setprio(1);
#pragma unroll
        for (int i = 0; i < 4; i++)
#pragma unroll
            for (int j = 0; j < 4; j++)
                acc[i][j] = __builtin_amdgcn_mfma_f32_16x16x32_bf16(
                    af[i], bfr[j], acc[i][j], 0, 0, 0);
        __builtin_amdgcn_s_setprio(0);
        sb = (sb == 2) ? 0 : sb + 1;
    }

    // ---- intra-block reduction: half-1 -> LDS -> half-0 adds, writes out.
    // Slot-major layout: float4 index = slot*256 + wl*64 + lane
    // (lane-consecutive 16B -> conflict-free b128 both directions).
    __syncthreads();                                // all K-loop LDS reads done
    float* rb = (float*)As;                         // 32KB per phase < 48KB
    const int rbase = (wl * 64 + lane) * 4;         // float offset within slot
#pragma unroll
    for (int p = 0; p < 2; p++) {
        if (half == 1) {
#pragma unroll
            for (int ii = 0; ii < 2; ii++)
#pragma unroll
                for (int j = 0; j < 4; j++)
                    *(f32x4*)&rb[(ii * 4 + j) * 1024 + rbase] = acc[p * 2 + ii][j];
        }
        __syncthreads();
        if (half == 0) {
#pragma unroll
            for (int ii = 0; ii < 2; ii++) {
                const int i = p * 2 + ii;
                const int rowb = row0 + wr * 64 + i * 16 + quad * 4;
#pragma unroll
                for (int j = 0; j < 4; j++) {
                    const f32x4 other = *(const f32x4*)&rb[(ii * 4 + j) * 1024 + rbase];
                    const int c = col0 + wc * 64 + j * 16 + l15;
#pragma unroll
                    for (int r = 0; r < 4; r++)
                        Outp[(size_t)(rowb + r) * D_MODEL + c] = acc[i][j][r] + other[r];
                }
            }
        }
        if (p == 0) __syncthreads();                // before phase-2 overwrite
    }
}

// ---------------------------------------------------------------------------
// Flash attention v5 (R7-proven): QBLK=64, 4 waves, zigzag qt balance.
// T13 defer-rescale, cvt_pk P-pack, per-lane l partial, setprio around MFMA.
// LDS 40 KB -> 4 blocks/CU. (R8: QBLK=128 regressed; keep 4 blocks/CU.)
// ---------------------------------------------------------------------------
__global__ __launch_bounds__(256) void flash_attn_kernel(
    const unsigned short* __restrict__ Q,
    const unsigned short* __restrict__ K,
    const unsigned short* __restrict__ Vt,
    unsigned short* __restrict__ O)
{
    const int idx = blockIdx.x;
    const int bh = idx & 31;
    const int qt2 = idx >> 5;
    const int hi = qt2 >> 3, lo = qt2 & 7;
    const int qt = (hi == 0) ? lo : (hi == 1) ? 31 - lo : (hi == 2) ? lo + 8 : 23 - lo;

    const int tid = threadIdx.x;
    const int w = tid >> 6, lane = tid & 63;
    const int l15 = lane & 15, quad = lane >> 4;

    __shared__ unsigned short Ks[2][4096];
    __shared__ unsigned short Vs[2][4096];
    __shared__ unsigned short Ps[4][1024];

    bf16x8 qf[2];
    {
        const unsigned short* qrow =
            Q + ((size_t)bh * SEQ + qt * 64 + w * 16 + l15) * HEAD_DIM;
        qf[0] = *(const bf16x8*)(qrow + quad * 8);
        qf[1] = *(const bf16x8*)(qrow + 32 + quad * 8);
    }

    const f32x4 zero4 = {0.f, 0.f, 0.f, 0.f};
    f32x4 o_acc[4] = {zero4, zero4, zero4, zero4};
    float m_i = -1e30f, l_i = 0.f;

    auto stage = [&](int bf, int kt_t) {
        const int key0 = kt_t * 64;
#pragma unroll
        for (int i = 0; i < 2; i++) {
            const int f = w * 2 + i;
            const int ct = f >> 1, kh = f & 1;
            gload_lds16(K + ((size_t)bh * SEQ + key0 + ct * 16 + l15) * HEAD_DIM
                          + kh * 32 + quad * 8,
                        &Ks[bf][f * 512 + lane * 8]);
            gload_lds16(Vt + ((size_t)bh * HEAD_DIM + ct * 16 + l15) * SEQ
                           + key0 + kh * 32 + quad * 8,
                        &Vs[bf][f * 512 + lane * 8]);
        }
    };

    stage(0, 0);
    int buf = 0;

    const int qg = qt * 64 + w * 16 + l15;

    for (int kt = 0; kt <= qt; kt++) {
        __syncthreads();
        if (kt < qt) stage(buf ^ 1, kt + 1);

        f32x4 st[4] = {zero4, zero4, zero4, zero4};
        __builtin_amdgcn_s_setprio(1);
#pragma unroll
        for (int kh = 0; kh < 2; kh++) {
#pragma unroll
            for (int ct = 0; ct < 4; ct++) {
                bf16x8 kf = *(const bf16x8*)&Ks[buf][(ct * 2 + kh) * 512 + lane * 8];
                st[ct] = __builtin_amdgcn_mfma_f32_16x16x32_bf16(kf, qf[kh], st[ct], 0, 0, 0);
            }
        }
        __builtin_amdgcn_s_setprio(0);

        float mt = -1e30f;
        if (kt == qt) {
#pragma unroll
            for (int ct = 0; ct < 4; ct++) {
#pragma unroll
                for (int r = 0; r < 4; r++) {
                    const int kg = kt * 64 + ct * 16 + quad * 4 + r;
                    float v = (kg > qg) ? -1e30f : st[ct][r];
                    st[ct][r] = v;
                    mt = fmaxf(mt, v);
                }
            }
        } else {
#pragma unroll
            for (int ct = 0; ct < 4; ct++)
#pragma unroll
                for (int r = 0; r < 4; r++)
                    mt = fmaxf(mt, st[ct][r]);
        }
        mt = fmaxf(mt, __shfl_xor(mt, 16));
        mt = fmaxf(mt, __shfl_xor(mt, 32));

        float mn = m_i;
        if (!__all(mt <= m_i + 8.0f)) {
            mn = fmaxf(m_i, mt);
            const float alpha = __expf(m_i - mn);
            m_i = mn;
            l_i *= alpha;
            float ar[4];
#pragma unroll
            for (int r = 0; r < 4; r++)
                ar[r] = __shfl(alpha, (lane & 48) | (quad * 4 + r));
#pragma unroll
            for (int dt = 0; dt < 4; dt++)
#pragma unroll
                for (int r = 0; r < 4; r++)
                    o_acc[dt][r] *= ar[r];
        }

        float ls = 0.f;
#pragma unroll
        for (int ct = 0; ct < 4; ct++) {
            const float p0 = __expf(st[ct][0] - mn);
            const float p1 = __expf(st[ct][1] - mn);
            const float p2 = __expf(st[ct][2] - mn);
            const float p3 = __expf(st[ct][3] - mn);
            ls += (p0 + p1) + (p2 + p3);
            uint2 pk2;
            pk2.x = cvtpk_bf16(p0, p1);
            pk2.y = cvtpk_bf16(p2, p3);
            const int addr = (ct >> 1) * 512 + ((ct & 1) * 2 + (quad >> 1)) * 128
                           + l15 * 8 + (quad & 1) * 4;
            *(uint2*)&Ps[w][addr] = pk2;
        }
        l_i += ls;

        __builtin_amdgcn_s_setprio(1);
#pragma unroll
        for (int kh = 0; kh < 2; kh++) {
            bf16x8 pa = *(const bf16x8*)&Ps[w][kh * 512 + quad * 128 + l15 * 8];
#pragma unroll
            for (int dt = 0; dt < 4; dt++) {
                bf16x8 vf = *(const bf16x8*)&Vs[buf][(dt * 2 + kh) * 512 + lane * 8];
                o_acc[dt] = __builtin_amdgcn_mfma_f32_16x16x32_bf16(pa, vf, o_acc[dt], 0, 0, 0);
            }
        }
        __builtin_amdgcn_s_setprio(0);
        buf ^= 1;
    }

    l_i += __shfl_xor(l_i, 16);
    l_i += __shfl_xor(l_i, 32);
    const float linv = 1.0f / l_i;
    float lr[4];
#pragma unroll
    for (int r = 0; r < 4; r++)
        lr[r] = __shfl(linv, (lane & 48) | (quad * 4 + r));

    const int b = bh >> 4, h = bh & 15;
#pragma unroll
    for (int r = 0; r < 4; r++) {
        const int q = qt * 64 + w * 16 + quad * 4 + r;
        unsigned short* orow = O + ((size_t)b * SEQ + q) * D_MODEL + h * HEAD_DIM;
#pragma unroll
        for (int dt = 0; dt < 4; dt++)
            orow[dt * 16 + l15] = f2bf_hw(o_acc[dt][r] * lr[r]);
    }
}

// ---------------------------------------------------------------------------
extern "C" void kernel_launch(void* const* d_in, const int* in_sizes, int n_in,
                              void* d_out, int out_size, void* d_ws, size_t ws_size,
                              hipStream_t stream) {
    const float* x      = (const float*)d_in[0];
    const float* w_qkv  = (const float*)d_in[1];
    const float* w_proj = (const float*)d_in[2];
    float* out = (float*)d_out;

    unsigned short* Xb  = (unsigned short*)d_ws;          // 4M shorts
    unsigned short* Wqt = Xb  + (size_t)4 * 1024 * 1024;  // 3M
    unsigned short* Wpt = Wqt + (size_t)3 * 1024 * 1024;  // 1M
    unsigned short* Qb  = Wpt + (size_t)1 * 1024 * 1024;  // 4M
    unsigned short* Kb  = Qb  + (size_t)4 * 1024 * 1024;  // 4M
    unsigned short* Vb  = Kb  + (size_t)4 * 1024 * 1024;  // 4M (spacer)
    unsigned short* Vtb = Vb  + (size_t)4 * 1024 * 1024;  // 4M (written by gemm)
    unsigned short* Ob  = Vtb + (size_t)4 * 1024 * 1024;  // 4M  (56 MB total)

    fused_convert_kernel<<<dim3(6144), 256, 0, stream>>>(
        x, Xb, w_qkv, Wqt, w_proj, Wpt);

    gemm_qkv_mfma<<<dim3(3 * D_MODEL / 128, BATCH * SEQ / 128), 256, 0, stream>>>(
        Xb, Wqt, Qb, Kb, Vtb);

    flash_attn_kernel<<<dim3(SEQ / 64 * BATCH * N_HEADS), 256, 0, stream>>>(
        Qb, Kb, Vtb, Ob);

    gemm_proj_fused<<<dim3(D_MODEL / 128, BATCH * SEQ / 128), 512, 0, stream>>>(
        Ob, Wpt, out);
}